// Round 4
// baseline (292.122 us; speedup 1.0000x reference)
//
#include <hip/hip_runtime.h>

// ---------------------------------------------------------------------------
// QTranBase: twin 3-layer MLPs via bf16 MFMA.
// R10: balance + fusion. R9 post-mortem: (1) Q-blocks (16 tiles) and
// V-blocks (8 tiles) paired same-type on CUs (work=mi*4+v, stride-32
// round-robin => v identical) -> ~25% CU idle; (2) prep's X-convert moves
// 192MB that need not exist. Fix: merge Q+V into one block per (mi,nhalf)
// -> 256 blocks, 1/CU, uniform work; layer1 stages A directly from f32
// states/actions (reg-load + rne cvt + swizzled ds_write_b128), X deleted.
// B stays global_load_lds with pre-swizzled source (R9, 0 conflicts).
// Ledger per tile t: issue A(t+1)[8]+Bdma(t+1)[4]; vmcnt(12) drains B(t)
// (compiler auto-waits rA deps); SBAR; compute; writeA(t+1); lgkmcnt(0);
// SBAR. Single counted drain per tile, full-tile cover, 2 barriers.
// ---------------------------------------------------------------------------

#define ROWS 32768
#define EMBED 512

using frag_ab = __attribute__((ext_vector_type(8))) short;   // 8 x bf16
using f32x4   = __attribute__((ext_vector_type(4))) float;   // MFMA C/D

__device__ __forceinline__ unsigned short f2bf(float f) {
    unsigned int u = __builtin_bit_cast(unsigned int, f);
    return (unsigned short)((u + 0x7fffu + ((u >> 16) & 1u)) >> 16);
}

__device__ __forceinline__ unsigned pk2rne(float lo, float hi) {
    return (unsigned)f2bf(lo) | ((unsigned)f2bf(hi) << 16);
}

__device__ __forceinline__ void async_copy16(const void* g, void* l) {
    // dest = wave-uniform LDS base; HW writes base + lane*16 (linear!)
    __builtin_amdgcn_global_load_lds(
        (const __attribute__((address_space(1))) unsigned int*)g,
        (__attribute__((address_space(3))) unsigned int*)l, 16, 0, 0);
}

#define VM12()  asm volatile("s_waitcnt vmcnt(12)" ::: "memory")
#define VM8()   asm volatile("s_waitcnt vmcnt(8)" ::: "memory")
#define VM0()   asm volatile("s_waitcnt vmcnt(0)" ::: "memory")
#define LGKM0() asm volatile("s_waitcnt lgkmcnt(0)" ::: "memory")
#define SBAR()  __builtin_amdgcn_s_barrier()

// ---------------------------------------------------------------------------
// prep: blocks [0,320) transpose weights via LDS tiles (coalesced both
// sides); [320,576) seed out with layer-3 bias. X is gone (fused into L1).
// ---------------------------------------------------------------------------
__global__ __launch_bounds__(256)
void prep(const float* __restrict__ Qw1, const float* __restrict__ Qw2,
          const float* __restrict__ Vw1, const float* __restrict__ Vw2,
          const float* __restrict__ qb3, const float* __restrict__ vb3,
          unsigned short* __restrict__ Qw1t, unsigned short* __restrict__ Qw2t,
          unsigned short* __restrict__ Vw1t, unsigned short* __restrict__ Vw2t,
          float* __restrict__ out) {
    const int b = blockIdx.x, tid = threadIdx.x;
    if (b < 320) {
        // 64x64 f32 tile transpose through LDS (+1 pad -> conflict-free cols)
        __shared__ float T[64][65];
        int tg = b;
        const float* W; unsigned short* O; int Krows, kt, nt;
        if (tg < 128) { W = Qw1; O = Qw1t; Krows = 1024; kt = tg >> 3; nt = tg & 7; }
        else {
            tg -= 128; int seg = tg >> 6, r = tg & 63;
            kt = r >> 3; nt = r & 7; Krows = 512;
            W = (seg == 0) ? Qw2 : (seg == 1) ? Vw1 : Vw2;
            O = (seg == 0) ? Qw2t : (seg == 1) ? Vw1t : Vw2t;
        }
        const int k0 = kt * 64, n0 = nt * 64;
        const int rr = tid >> 4, c4 = (tid & 15) * 4;
#pragma unroll
        for (int p = 0; p < 4; ++p) {
            float4 v = *(const float4*)&W[(size_t)(k0 + p * 16 + rr) * 512 + n0 + c4];
            T[p * 16 + rr][c4]     = v.x;
            T[p * 16 + rr][c4 + 1] = v.y;
            T[p * 16 + rr][c4 + 2] = v.z;
            T[p * 16 + rr][c4 + 3] = v.w;
        }
        __syncthreads();
        const int n = tid >> 2, kc = (tid & 3) * 16;
        unsigned pk[8];
#pragma unroll
        for (int j = 0; j < 8; ++j)
            pk[j] = pk2rne(T[kc + 2 * j][n], T[kc + 2 * j + 1][n]);
        uint4* dst = (uint4*)(O + (size_t)(n0 + n) * Krows + k0 + kc);
        dst[0] = make_uint4(pk[0], pk[1], pk[2], pk[3]);
        dst[1] = make_uint4(pk[4], pk[5], pk[6], pk[7]);
    } else {
        int i = (b - 320) * 256 + tid;
        out[i] = (i < ROWS) ? qb3[0] : vb3[0];
    }
}

// 256 blocks -> (mi, nhalf): bijective XCD swizzle (256 = 8*32); the two
// n-halves of one mi land adjacently on one XCD's L2 (shared A panel).
__device__ __forceinline__ void decode_work(int bid, int& mi, int& n) {
    int work = ((bid & 7) << 5) | (bid >> 3);
    mi = work >> 1; n = work & 1;
}

// ---------------------------------------------------------------------------
// Layer 1 (Q then V per block): h1 = relu([states|actions] @ Wt^T + bias).
// 256x256 tile, BK=64, dbuf. A: f32 global -> regs -> cvt -> swizzled
// ds_write_b128 (write slot c^(r&7), read slot g^(r&7): same involution as
// the B-side DMA swizzle). B: global_load_lds, pre-swizzled source.
// ---------------------------------------------------------------------------
__global__ __launch_bounds__(512, 2)
void layer1(const float* __restrict__ states, const float* __restrict__ actions,
            const unsigned short* __restrict__ Qw1t,
            const unsigned short* __restrict__ Vw1t,
            const float* __restrict__ Qb1, const float* __restrict__ Vb1,
            unsigned short* __restrict__ h1Q, unsigned short* __restrict__ h1V) {
    __shared__ __align__(16) char smem[131072];   // A dbuf 64KB @0, B dbuf 64KB @65536
    const int tid = threadIdx.x, wave = tid >> 6, lane = tid & 63;
    int mi, nh; decode_work(blockIdx.x, mi, nh);
    const int bm = mi * 256, bn = nh * 256;
    const int im = wave >> 2, in = wave & 3;      // 2M x 4N waves
    const int lrow = lane & 15, quad = lane >> 4;

    // A staging geometry: lane covers rows arow+64q, 8 consecutive f32.
    const int arow = wave * 8 + (lane >> 3);
    const int acol = (lane & 7) * 8;
    const size_t aOff = (size_t)(bm + arow) * 512 + acol;

    // B DMA geometry: row srow, 16B unit (lane&7), source pre-swizzled.
    const int srow = wave * 8 + (lane >> 3);
    const int scol = (((lane & 7) ^ ((lane >> 3) & 7)) << 4);

    float4 rA[4][2];
    frag_ab a[4][2], b0[2][2], b1[2][2];
    f32x4 acc[8][4] = {};

    auto loadA = [&](const float* p) {
#pragma unroll
        for (int q = 0; q < 4; ++q) {
            const float* s = p + (size_t)(64 * q) * 512;
            rA[q][0] = *(const float4*)s;
            rA[q][1] = *(const float4*)(s + 4);
        }
    };
    auto writeA = [&](int b) {
#pragma unroll
        for (int q = 0; q < 4; ++q) {
            const int R = arow + 64 * q, half = R >> 7, r = R & 127;
            const int c = (lane & 7) ^ (r & 7);
            *(uint4*)(smem + b * 32768 + half * 16384 + r * 128 + (c << 4)) =
                make_uint4(pk2rne(rA[q][0].x, rA[q][0].y),
                           pk2rne(rA[q][0].z, rA[q][0].w),
                           pk2rne(rA[q][1].x, rA[q][1].y),
                           pk2rne(rA[q][1].z, rA[q][1].w));
        }
    };
    auto readA = [&](int b, int mh) {
        const char* base = smem + b * 32768 + im * 16384;
#pragma unroll
        for (int i = 0; i < 4; ++i) {
            const int r = mh * 64 + i * 16 + lrow;
#pragma unroll
            for (int s = 0; s < 2; ++s)
                a[i][s] = *(const frag_ab*)(base + r * 128 +
                              (((s * 4 + quad) ^ (r & 7)) << 4));
        }
    };
    auto readB = [&](int b, int nhh, frag_ab bb[2][2]) {
#pragma unroll
        for (int j = 0; j < 2; ++j) {
            const int nr = in * 64 + nhh * 32 + j * 16 + lrow;
            const char* base = smem + 65536 + b * 32768 + (nr >> 7) * 16384;
            const int r = nr & 127;
#pragma unroll
            for (int s = 0; s < 2; ++s)
                bb[j][s] = *(const frag_ab*)(base + r * 128 +
                               (((s * 4 + quad) ^ (r & 7)) << 4));
        }
    };
    auto mma = [&](int mh, int nhh, frag_ab bb[2][2]) {
        __builtin_amdgcn_s_setprio(1);
#pragma unroll
        for (int s = 0; s < 2; ++s)
#pragma unroll
            for (int i = 0; i < 4; ++i)
#pragma unroll
                for (int j = 0; j < 2; ++j)
                    acc[mh * 4 + i][nhh * 2 + j] =
                        __builtin_amdgcn_mfma_f32_16x16x32_bf16(
                            a[i][s], bb[j][s], acc[mh * 4 + i][nhh * 2 + j],
                            0, 0, 0);
        __builtin_amdgcn_s_setprio(0);
    };

    // One fused K-sweep: tiles [0,nt0) from aP0, [nt0,nt0+nt1) from aP1.
    auto run = [&](const float* aP0, const float* aP1, int nt0, int nt1,
                   const unsigned short* Wt, int ldbE) {
        const int NT = nt0 + nt1;
        const int ldbB = ldbE * 2;
        const char* gB = (const char*)Wt + (size_t)(bn + srow) * ldbB + scol;
        auto stageB = [&](int b) {   // 4 vmem per wave
#pragma unroll
            for (int h = 0; h < 2; ++h) {
                const char* g = gB + (size_t)(h * 128) * ldbB;
                char* l = smem + 65536 + wave * 1024 + b * 32768 + h * 16384;
                async_copy16(g, l);
                async_copy16(g + (size_t)64 * ldbB, l + 8192);
            }
            gB += 128;
        };
        auto aTile = [&](int kt) {
            return (kt < nt0) ? aP0 + aOff + kt * 64
                              : aP1 + aOff + (kt - nt0) * 64;
        };
        // prologue: tile 0 -> regs + bufB0; A cvt+write (compiler waits rA).
        loadA(aTile(0));
        stageB(0);
        writeA(0);
        LGKM0();
        for (int t = 0; t < NT; ++t) {
            const bool more = t + 1 < NT;
            if (more) { loadA(aTile(t + 1)); stageB((t + 1) & 1); }
            // drain B(t): >=12 new vmem issued above when more; else full.
            if (more) VM12(); else VM0();
            SBAR();              // bufA(t) written (prev iter), bufB(t) landed
            const int bb = t & 1;
            readA(bb, 0); readB(bb, 0, b0);
            mma(0, 0, b0);
            readB(bb, 1, b1);
            mma(0, 1, b1);
            readA(bb, 1);
            mma(1, 1, b1);
            mma(1, 0, b0);
            if (more) writeA((t + 1) & 1);   // other buf; its readers done
            LGKM0();             // my ds_reads(t) + ds_writes(t+1) complete
            SBAR();              // everyone done with buf t
        }
    };

    auto epilogue = [&](const float* bias, unsigned short* H) {
#pragma unroll
        for (int j = 0; j < 4; ++j) {
            const int col = bn + in * 64 + j * 16 + lrow;
            const float bc = bias[col];
#pragma unroll
            for (int i = 0; i < 8; ++i) {
                const int row0 = bm + im * 128 + i * 16 + quad * 4;
#pragma unroll
                for (int r = 0; r < 4; ++r) {
                    float val = acc[i][j][r] + bc;
                    val = val > 0.0f ? val : 0.0f;
                    H[(size_t)(row0 + r) * EMBED + col] = f2bf(val);
                }
            }
        }
    };

    // Q: K=1024 (states cols 0-511, actions cols 512-1023)
    run(states, actions, 8, 8, Qw1t, 1024);
    epilogue(Qb1, h1Q);
#pragma unroll
    for (int i = 0; i < 8; ++i)
#pragma unroll
        for (int j = 0; j < 4; ++j) acc[i][j] = f32x4{0.f, 0.f, 0.f, 0.f};
    // V: K=512 (states only)
    run(states, states, 8, 0, Vw1t, 512);
    epilogue(Vb1, h1V);
}

// ---------------------------------------------------------------------------
// Layer 2+3 (Q then V per block): out[row] += sum_n relu(h1@W2^T+b2)[n]*w3[n]
// R9 gemm (all-DMA, distance-2, vmcnt(8)) reused verbatim per segment.
// ---------------------------------------------------------------------------
__device__ __forceinline__ void gemm_256(
    const unsigned short* __restrict__ A,
    const unsigned short* __restrict__ Bt,
    int bm, int bn, char* smb, f32x4 acc[8][4])
{
    const int tid = threadIdx.x, wave = tid >> 6, lane = tid & 63;
    const int im = wave >> 2, in = wave & 3;
    const int lrow = lane & 15, quad = lane >> 4;

    const int srow = wave * 8 + (lane >> 3);
    const int scol = (((lane & 7) ^ ((lane >> 3) & 7)) << 4);
    const char* gA = (const char*)A + (size_t)(bm + srow) * 1024 + scol;
    const char* gB = (const char*)Bt + (size_t)(bn + srow) * 1024 + scol;
    char* ldsAw = smb + wave * 1024;
    char* ldsBw = smb + 65536 + wave * 1024;

    auto stageTile = [&](int b) {    // 8 vmem per wave
#pragma unroll
        for (int h = 0; h < 2; ++h) {
            const char* g = gA + (size_t)(h * 128) * 1024;
            char* l = ldsAw + b * 32768 + h * 16384;
            async_copy16(g, l);
            async_copy16(g + (size_t)64 * 1024, l + 8192);
        }
#pragma unroll
        for (int h = 0; h < 2; ++h) {
            const char* g = gB + (size_t)(h * 128) * 1024;
            char* l = ldsBw + b * 32768 + h * 16384;
            async_copy16(g, l);
            async_copy16(g + (size_t)64 * 1024, l + 8192);
        }
        gA += 128; gB += 128;
    };

    frag_ab a[4][2], b0[2][2], b1[2][2];

    auto readA = [&](int b, int mh) {
        const char* base = smb + b * 32768 + im * 16384;
#pragma unroll
        for (int i = 0; i < 4; ++i) {
            const int r = mh * 64 + i * 16 + lrow;
#pragma unroll
            for (int s = 0; s < 2; ++s)
                a[i][s] = *(const frag_ab*)(base + r * 128 +
                              (((s * 4 + quad) ^ (r & 7)) << 4));
        }
    };
    auto readB = [&](int b, int nh, frag_ab bb[2][2]) {
#pragma unroll
        for (int j = 0; j < 2; ++j) {
            const int nr = in * 64 + nh * 32 + j * 16 + lrow;
            const char* base = smb + 65536 + b * 32768 + (nr >> 7) * 16384;
            const int r = nr & 127;
#pragma unroll
            for (int s = 0; s < 2; ++s)
                bb[j][s] = *(const frag_ab*)(base + r * 128 +
                               (((s * 4 + quad) ^ (r & 7)) << 4));
        }
    };
    auto mma = [&](int mh, int nh, frag_ab bb[2][2]) {
        __builtin_amdgcn_s_setprio(1);
#pragma unroll
        for (int s = 0; s < 2; ++s)
#pragma unroll
            for (int i = 0; i < 4; ++i)
#pragma unroll
                for (int j = 0; j < 2; ++j)
                    acc[mh * 4 + i][nh * 2 + j] =
                        __builtin_amdgcn_mfma_f32_16x16x32_bf16(
                            a[i][s], bb[j][s], acc[mh * 4 + i][nh * 2 + j],
                            0, 0, 0);
        __builtin_amdgcn_s_setprio(0);
    };

    stageTile(0);
    stageTile(1);

    const int NT = 8;   // K=512
    int buf = 0;
    for (int t = 0; t < NT; ++t) {
        if (t + 1 < NT) VM8(); else VM0();
        SBAR();
        readA(buf, 0); readB(buf, 0, b0);
        mma(0, 0, b0);
        readB(buf, 1, b1);
        mma(0, 1, b1);
        readA(buf, 1);
        mma(1, 1, b1);
        mma(1, 0, b0);
        SBAR();
        if (t + 2 < NT) stageTile(buf);
        buf ^= 1;
    }
}

__global__ __launch_bounds__(512, 2)
void layer2(const unsigned short* __restrict__ h1Q,
            const unsigned short* __restrict__ h1V,
            const unsigned short* __restrict__ Qw2t,
            const unsigned short* __restrict__ Vw2t,
            const float* __restrict__ Qb2, const float* __restrict__ Vb2,
            const float* __restrict__ Qw3, const float* __restrict__ Vw3,
            float* __restrict__ out) {
    __shared__ __align__(16) char smem[131072];
    const int tid = threadIdx.x, wave = tid >> 6, lane = tid & 63;
    int mi, nh; decode_work(blockIdx.x, mi, nh);
    const int bm = mi * 256, bn = nh * 256;
    const int im = wave >> 2, in = wave & 3;
    const int lrow = lane & 15, quad = lane >> 4;

    f32x4 acc[8][4] = {};

    auto epilogue = [&](const float* bias, const float* w3, float* op) {
        float bc[4], wc[4];
#pragma unroll
        for (int j = 0; j < 4; ++j) {
            const int col = bn + in * 64 + j * 16 + lrow;
            bc[j] = bias[col];
            wc[j] = w3[col];
        }
#pragma unroll
        for (int i = 0; i < 8; ++i) {
#pragma unroll
            for (int r = 0; r < 4; ++r) {
                float s = 0.0f;
#pragma unroll
                for (int j = 0; j < 4; ++j) {
                    float val = acc[i][j][r] + bc[j];
                    val = val > 0.0f ? val : 0.0f;
                    s += val * wc[j];
                }
#pragma unroll
                for (int m = 1; m < 16; m <<= 1) s += __shfl_xor(s, m, 64);
                if (lrow == 0)
                    atomicAdd(&op[bm + im * 128 + i * 16 + quad * 4 + r], s);
            }
        }
    };

    gemm_256(h1Q, Qw2t, bm, bn, smem, acc);
    epilogue(Qb2, Qw3, out);
#pragma unroll
    for (int i = 0; i < 8; ++i)
#pragma unroll
        for (int j = 0; j < 4; ++j) acc[i][j] = f32x4{0.f, 0.f, 0.f, 0.f};
    gemm_256(h1V, Vw2t, bm, bn, smem, acc);
    epilogue(Vb2, Vw3, out + ROWS);
}

extern "C" void kernel_launch(void* const* d_in, const int* in_sizes, int n_in,
                              void* d_out, int out_size, void* d_ws, size_t ws_size,
                              hipStream_t stream) {
    const float* states  = (const float*)d_in[0];
    const float* actions = (const float*)d_in[1];
    const float* Qw1 = (const float*)d_in[2];
    const float* Qb1 = (const float*)d_in[3];
    const float* Qw2 = (const float*)d_in[4];
    const float* Qb2 = (const float*)d_in[5];
    const float* Qw3 = (const float*)d_in[6];
    const float* Qb3 = (const float*)d_in[7];
    const float* Vw1 = (const float*)d_in[8];
    const float* Vb1 = (const float*)d_in[9];
    const float* Vw2 = (const float*)d_in[10];
    const float* Vb2 = (const float*)d_in[11];
    const float* Vw3 = (const float*)d_in[12];
    const float* Vb3 = (const float*)d_in[13];
    float* out = (float*)d_out;

    // workspace layout (bytes): h1Q 32MB @0, h1V 32MB @32M, weights after
    char* ws = (char*)d_ws;
    unsigned short* h1Q  = (unsigned short*)ws;
    unsigned short* h1V  = (unsigned short*)(ws + 33554432);
    unsigned short* Qw1t = (unsigned short*)(ws + 67108864);
    unsigned short* Qw2t = Qw1t + 512 * 1024;
    unsigned short* Vw1t = Qw2t + 512 * 512;
    unsigned short* Vw2t = Vw1t + 512 * 512;

    prep<<<dim3(576), dim3(256), 0, stream>>>(Qw1, Qw2, Vw1, Vw2, Qb3, Vb3,
                                              Qw1t, Qw2t, Vw1t, Vw2t, out);

    layer1<<<dim3(256), dim3(512), 0, stream>>>(states, actions, Qw1t, Vw1t,
                                                Qb1, Vb1, h1Q, h1V);
    layer2<<<dim3(256), dim3(512), 0, stream>>>(h1Q, h1V, Qw2t, Vw2t,
                                                Qb2, Vb2, Qw3, Vw3, out);
}